// Round 3
// baseline (459.144 us; speedup 1.0000x reference)
//
#include <hip/hip_runtime.h>

#define NN 100000
#define NE 1600000
#define DF 32
#define KIT 5
#define MU 0.01f
#define NSLOT 256
#define NV4 (NN * DF / 4)
#define ELLW 36
#define AUXCAP 65536
#define NSLICE 8
#define SLICEN (NN / NSLICE)   // 12500 nodes/slice
#define NSUB 20
#define SUBN (SLICEN / NSUB)   // 625 nodes per fill-block (exclusive ownership)
#define NBLKA (NE / 256)       // 6250 blocks in pass A, exactly 256 edges each
#define SEGW 64                // per-block per-slice segment capacity (mean fill 32)
#define INVALID_PK 0xffffffffu // sentinel: rl-field = 32767 >= SLICEN, never valid

typedef float f32x4 __attribute__((ext_vector_type(4)));

// ---------- one-time ELL build (edge_index is iteration-invariant) ----------

__global__ __launch_bounds__(64) void zero_kernel(int* __restrict__ p, int n) {
    int i = blockIdx.x * blockDim.x + threadIdx.x;
    if (i < n) p[i] = 0;
}

// Pass A: single streaming scan; bin edges into 8 slice-buckets. Zero global
// atomics in the common path: wave ballot -> per-wave per-bucket counts -> LDS
// prefix across the 4 waves -> LDS-staged segments -> fully-coalesced 256B
// segment writes. Unused slots carry INVALID_PK sentinels (so no cnts array).
// Segment overflow (P ~ 1e-9/block at Poisson) spills to aux.
// Edge packed to 4B: (r_local<14b)<<17 | c(17b). Bucket array (8*NBLKA*SEGW*4B
// = 12.8MB) aliases S, which is dead until the first agg_kernel overwrites it.
__global__ __launch_bounds__(256) void ell_part_kernel(const int* __restrict__ row,
                                                       const int* __restrict__ col,
                                                       unsigned int* __restrict__ buck,
                                                       int* __restrict__ auxcnt,
                                                       int2* __restrict__ aux) {
    __shared__ int wcnt[4][8];
    __shared__ int woff[4][8];
    __shared__ unsigned int sseg[8][SEGW];       // 2KB staging
    const int t = threadIdx.x;
    const int w = t >> 6;
    const int lane = t & 63;

    ((unsigned int*)sseg)[t] = INVALID_PK;
    ((unsigned int*)sseg)[t + 256] = INVALID_PK;

    const int e = blockIdx.x * 256 + t;          // grid is exactly NE/256
    const int r = __builtin_nontemporal_load(&row[e]);
    const int c = __builtin_nontemporal_load(&col[e]);
    const int b = r / SLICEN;                    // 0..7
    const int rl = r - b * SLICEN;               // < 12500
    const unsigned int packed = ((unsigned int)rl << 17) | (unsigned int)c;

    int myprefix = 0;
    #pragma unroll
    for (int k = 0; k < 8; ++k) {
        const unsigned long long mk = __ballot(b == k);
        if (lane == 0) wcnt[w][k] = __popcll(mk);
        if (k == b) myprefix = __popcll(mk & ((1ull << lane) - 1ull));
    }
    __syncthreads();
    if (t < 32) {
        const int w2 = t >> 3, k = t & 7;
        int o = 0;
        for (int w3 = 0; w3 < w2; ++w3) o += wcnt[w3][k];
        woff[w2][k] = o;
    }
    __syncthreads();

    const int pos = woff[w][b] + myprefix;
    if (pos < SEGW) {
        sseg[b][pos] = packed;
    } else {
        const int a = atomicAdd(auxcnt, 1);      // a.s. never
        if (a < AUXCAP) aux[a] = make_int2(r, c);
    }
    __syncthreads();

    // write out 8 segments x 256B, fully coalesced (incl. sentinels)
    #pragma unroll
    for (int k = 0; k < 2; ++k) {
        const int idx = t + k * 256;
        const int bb = idx >> 6;
        const int j = idx & 63;
        buck[((size_t)bb * NBLKA + blockIdx.x) * SEGW + j] = sseg[bb][j];
    }
}

// Pass B: 8 slices x 20 sub-ranges; each block EXCLUSIVELY owns 625 nodes.
// It scans its slice's bucket stream (L2-shared across the 20 co-XCD blocks,
// slice = bid&7 pins to one XCD) and counts/places edges with LDS atomics —
// zero device-scope RMWs (R2 post-mortem: 1.6M far-atomics = the invariant
// 69us). degc is written wholesale by the owner (plain coalesced stores), so
// no zero-init of degc is needed either. 1024 threads = 16 waves for latency
// hiding; one wave per segment, depth-1 prefetch.
__global__ __launch_bounds__(1024) void ell_fill_kernel(const unsigned int* __restrict__ buck,
                                                        int* __restrict__ degc,
                                                        int* __restrict__ colell,
                                                        int* __restrict__ auxcnt,
                                                        int2* __restrict__ aux) {
    __shared__ int lcnt[SUBN];                   // 2.5KB
    const int t = threadIdx.x;
    const int s = blockIdx.x & (NSLICE - 1);
    const int sub = blockIdx.x >> 3;             // 0..19
    const int lane = t & 63;
    const int wid = t >> 6;                      // 0..15
    const int lo = sub * SUBN;
    const int hi = lo + SUBN;

    for (int i = t; i < SUBN; i += 1024) lcnt[i] = 0;
    __syncthreads();

    const unsigned int* sp = buck + (size_t)s * NBLKA * SEGW;
    int blk = wid;
    unsigned int pk = sp[(size_t)blk * SEGW + lane];
    for (; blk < NBLKA; blk += 16) {
        const int nb = blk + 16;
        const unsigned int nx = (nb < NBLKA) ? sp[(size_t)nb * SEGW + lane] : INVALID_PK;
        const int rl = (int)(pk >> 17);          // sentinel -> 32767, fails hi check
        if (rl >= lo && rl < hi) {
            const int c = (int)(pk & 0x1ffffu);
            const int pos = atomicAdd(&lcnt[rl - lo], 1);
            const int r = s * SLICEN + rl;
            if (pos < ELLW) {
                colell[r * ELLW + pos] = c;
            } else {
                const int a = atomicAdd(auxcnt, 1);
                if (a < AUXCAP) aux[a] = make_int2(r, c);
            }
        }
        pk = nx;
    }
    __syncthreads();
    for (int i = t; i < SUBN; i += 1024) degc[s * SLICEN + lo + i] = lcnt[i];
}

// ---------- bf16 shadow helpers ----------

__device__ __forceinline__ unsigned int pack2bf(float a, float b) {
    unsigned int ua = __float_as_uint(a);
    unsigned int ub = __float_as_uint(b);
    return ((ua + 0x8000u) >> 16) | (((ub + 0x8000u) >> 16) << 16);
}

__device__ __forceinline__ void unpack8(uint4 v, float* f) {
    f[0] = __uint_as_float(v.x << 16);
    f[1] = __uint_as_float(v.x & 0xffff0000u);
    f[2] = __uint_as_float(v.y << 16);
    f[3] = __uint_as_float(v.y & 0xffff0000u);
    f[4] = __uint_as_float(v.z << 16);
    f[5] = __uint_as_float(v.z & 0xffff0000u);
    f[6] = __uint_as_float(v.w << 16);
    f[7] = __uint_as_float(v.w & 0xffff0000u);
}

__global__ __launch_bounds__(256) void tobf16_kernel(const float* __restrict__ h,
                                                     uint2* __restrict__ hb) {
    int i = blockIdx.x * blockDim.x + threadIdx.x;
    if (i < NV4) {
        const f32x4 v = __builtin_nontemporal_load(((const f32x4*)h) + i);
        hb[i] = make_uint2(pack2bf(v.x, v.y), pack2bf(v.z, v.w));
    }
}

// ---------- per-iteration ----------

// One 32-lane group per NODE PAIR. lane = q(3b)*4 + f2(2b); a lane-quad covers
// one 64B bf16 row (uint4/lane). All 10 loads issued before consumption.
// colell reads are nt (streamed once); S stores stay TEMPORAL (update re-reads
// S within ~10us -> keep in L2; R2's nt store here was a regression).
__global__ __launch_bounds__(256) void agg_kernel(const uint4* __restrict__ hb4,
                                                  const int* __restrict__ degc,
                                                  const int* __restrict__ colell,
                                                  float* __restrict__ S,
                                                  int* __restrict__ maxslots) {
    const int lane = threadIdx.x & 31;
    const int q = lane >> 2;
    const int f2 = lane & 3;
    const int pair = (blockIdx.x * blockDim.x + threadIdx.x) >> 5;
    const int n0 = pair * 2;
    const int n1 = n0 + 1;

    const int d0 = min(degc[n0], ELLW);
    const int d1 = min(degc[n1], ELLW);

    // head loads, all independent
    const int ca = (lane < d0) ? __builtin_nontemporal_load(&colell[n0 * ELLW + lane]) : n0;
    const int cb = (lane < d1) ? __builtin_nontemporal_load(&colell[n1 * ELLW + lane]) : n1;
    const uint4 hru0 = hb4[n0 * 4 + f2];
    const uint4 hru1 = hb4[n1 * 4 + f2];

    uint4 u0[4], u1[4];
    #pragma unroll
    for (int j = 0; j < 4; ++j) u0[j] = hb4[__shfl(ca, 8 * j + q, 32) * 4 + f2];
    #pragma unroll
    for (int j = 0; j < 4; ++j) u1[j] = hb4[__shfl(cb, 8 * j + q, 32) * 4 + f2];

    float hr0[8], hr1[8];
    unpack8(hru0, hr0);
    unpack8(hru1, hr1);

    float acc0[8], acc1[8];
    #pragma unroll
    for (int i = 0; i < 8; ++i) { acc0[i] = 0.0f; acc1[i] = 0.0f; }
    float nmax = 0.0f;

    #pragma unroll
    for (int j = 0; j < 4; ++j) {
        float d[8];
        unpack8(u0[j], d);
        float s = 0.0f;
        #pragma unroll
        for (int i = 0; i < 8; ++i) {
            d[i] = hr0[i] - d[i];
            s = fmaf(d[i], d[i], s);
        }
        s += __shfl_xor(s, 1, 32);
        s += __shfl_xor(s, 2, 32);
        const float n = fmaxf(sqrtf(s), 1e-6f);
        nmax = fmaxf(nmax, n);
        const float w = rsqrtf(n);
        #pragma unroll
        for (int i = 0; i < 8; ++i) acc0[i] = fmaf(-d[i], w, acc0[i]);
    }
    #pragma unroll
    for (int j = 0; j < 4; ++j) {
        float d[8];
        unpack8(u1[j], d);
        float s = 0.0f;
        #pragma unroll
        for (int i = 0; i < 8; ++i) {
            d[i] = hr1[i] - d[i];
            s = fmaf(d[i], d[i], s);
        }
        s += __shfl_xor(s, 1, 32);
        s += __shfl_xor(s, 2, 32);
        const float n = fmaxf(sqrtf(s), 1e-6f);
        nmax = fmaxf(nmax, n);
        const float w = rsqrtf(n);
        #pragma unroll
        for (int i = 0; i < 8; ++i) acc1[i] = fmaf(-d[i], w, acc1[i]);
    }

    // tails: edges 32..d-1 (at most one 8-edge step since ELLW=36)
    for (int k = 32; k < d0; k += 8) {
        const int ei = k + q;
        const int c = (ei < d0) ? __builtin_nontemporal_load(&colell[n0 * ELLW + ei]) : n0;
        const uint4 uu = hb4[c * 4 + f2];
        float d[8];
        unpack8(uu, d);
        float s = 0.0f;
        #pragma unroll
        for (int i = 0; i < 8; ++i) {
            d[i] = hr0[i] - d[i];
            s = fmaf(d[i], d[i], s);
        }
        s += __shfl_xor(s, 1, 32);
        s += __shfl_xor(s, 2, 32);
        const float n = fmaxf(sqrtf(s), 1e-6f);
        nmax = fmaxf(nmax, n);
        const float w = rsqrtf(n);
        #pragma unroll
        for (int i = 0; i < 8; ++i) acc0[i] = fmaf(-d[i], w, acc0[i]);
    }
    for (int k = 32; k < d1; k += 8) {
        const int ei = k + q;
        const int c = (ei < d1) ? __builtin_nontemporal_load(&colell[n1 * ELLW + ei]) : n1;
        const uint4 uu = hb4[c * 4 + f2];
        float d[8];
        unpack8(uu, d);
        float s = 0.0f;
        #pragma unroll
        for (int i = 0; i < 8; ++i) {
            d[i] = hr1[i] - d[i];
            s = fmaf(d[i], d[i], s);
        }
        s += __shfl_xor(s, 1, 32);
        s += __shfl_xor(s, 2, 32);
        const float n = fmaxf(sqrtf(s), 1e-6f);
        nmax = fmaxf(nmax, n);
        const float w = rsqrtf(n);
        #pragma unroll
        for (int i = 0; i < 8; ++i) acc1[i] = fmaf(-d[i], w, acc1[i]);
    }

    // cross-quad reduce (quads hold different edges, same feats)
    #pragma unroll
    for (int m = 4; m < 32; m <<= 1) {
        #pragma unroll
        for (int i = 0; i < 8; ++i) {
            acc0[i] += __shfl_xor(acc0[i], m, 32);
            acc1[i] += __shfl_xor(acc1[i], m, 32);
        }
    }
    if (q == 0) {
        ((float4*)S)[n0 * 8 + f2 * 2] = make_float4(acc0[0], acc0[1], acc0[2], acc0[3]);
        ((float4*)S)[n0 * 8 + f2 * 2 + 1] = make_float4(acc0[4], acc0[5], acc0[6], acc0[7]);
        ((float4*)S)[n1 * 8 + f2 * 2] = make_float4(acc1[0], acc1[1], acc1[2], acc1[3]);
        ((float4*)S)[n1 * 8 + f2 * 2 + 1] = make_float4(acc1[4], acc1[5], acc1[6], acc1[7]);
    }

    nmax = fmaxf(nmax, __shfl_xor(nmax, 4, 32));
    nmax = fmaxf(nmax, __shfl_xor(nmax, 8, 32));
    nmax = fmaxf(nmax, __shfl_xor(nmax, 16, 32));
    nmax = fmaxf(nmax, __shfl_xor(nmax, 32, 64));
    if ((threadIdx.x & 63) == 0) {
        // positive floats order like ints; 0xAA poison is negative -> loses
        atomicMax(&maxslots[blockIdx.x & (NSLOT - 1)], __float_as_int(nmax));
    }
}

// overflow edges (deg > ELLW or segment spill): full per-edge norm + atomic
// accumulate into S. Almost surely empty; grid-stride guarantees coverage.
// Runs AFTER agg (its plain S stores) and BEFORE update.
__global__ __launch_bounds__(256) void aux_kernel(const uint2* __restrict__ hb,
                                                  const int2* __restrict__ aux,
                                                  const int* __restrict__ auxcnt,
                                                  float* __restrict__ S,
                                                  int* __restrict__ maxslots) {
    const int n = min(*auxcnt, AUXCAP);
    for (int i = blockIdx.x * blockDim.x + threadIdx.x; i < n;
         i += gridDim.x * blockDim.x) {
        const int r = aux[i].x;
        const int c = aux[i].y;
        float d[32];
        float s = 0.0f;
        for (int j = 0; j < 8; ++j) {
            const uint2 ur = hb[r * 8 + j];
            const uint2 uc = hb[c * 8 + j];
            float fr[4], fc[4];
            fr[0] = __uint_as_float(ur.x << 16);
            fr[1] = __uint_as_float(ur.x & 0xffff0000u);
            fr[2] = __uint_as_float(ur.y << 16);
            fr[3] = __uint_as_float(ur.y & 0xffff0000u);
            fc[0] = __uint_as_float(uc.x << 16);
            fc[1] = __uint_as_float(uc.x & 0xffff0000u);
            fc[2] = __uint_as_float(uc.y << 16);
            fc[3] = __uint_as_float(uc.y & 0xffff0000u);
            #pragma unroll
            for (int k = 0; k < 4; ++k) {
                d[j * 4 + k] = fr[k] - fc[k];
                s = fmaf(d[j * 4 + k], d[j * 4 + k], s);
            }
        }
        const float nn = fmaxf(sqrtf(s), 1e-6f);
        atomicMax(&maxslots[i & (NSLOT - 1)], __float_as_int(nn));
        const float w = rsqrtf(nn);
        for (int f = 0; f < 32; ++f) atomicAdd(&S[r * DF + f], -d[f] * w);
    }
}

// h_out = h_in - MU*sqrt(M)*S (fp32), plus refresh of the bf16 shadow.
// Plain (temporal) loads/stores throughout — R1-proven form.
__global__ __launch_bounds__(256) void update_kernel(const float4* __restrict__ hcur,
                                                     float4* __restrict__ hnxt,
                                                     uint2* __restrict__ hb,
                                                     const float4* __restrict__ S,
                                                     const int* __restrict__ slots) {
    const int t = threadIdx.x;
    int v = slots[t];
    #pragma unroll
    for (int m = 32; m > 0; m >>= 1) v = max(v, __shfl_xor(v, m, 64));
    __shared__ int sm[4];
    __shared__ float sscale;
    if ((t & 63) == 0) sm[t >> 6] = v;
    __syncthreads();
    if (t == 0) {
        int bm = max(max(sm[0], sm[1]), max(sm[2], sm[3]));
        sscale = MU * sqrtf(__int_as_float(bm));
    }
    __syncthreads();
    const float scale = sscale;
    const int i = blockIdx.x * blockDim.x + t;
    if (i < NV4) {
        const float4 hv = hcur[i];
        const float4 sv = S[i];
        float4 o;
        o.x = hv.x - scale * sv.x;
        o.y = hv.y - scale * sv.y;
        o.z = hv.z - scale * sv.z;
        o.w = hv.w - scale * sv.w;
        hnxt[i] = o;
        hb[i] = make_uint2(pack2bf(o.x, o.y), pack2bf(o.z, o.w));
    }
}

extern "C" void kernel_launch(void* const* d_in, const int* in_sizes, int n_in,
                              void* d_out, int out_size, void* d_ws, size_t ws_size,
                              hipStream_t stream) {
    const float* h_in = (const float*)d_in[0];
    const int* row = (const int*)d_in[1];
    const int* col = row + NE;
    float* out = (float*)d_out;

    float* S = (float*)d_ws;                         // NN*DF f32   (12.8 MB)
    int* maxslots = (int*)(S + NN * DF);             // KIT*NSLOT
    int* degc = maxslots + KIT * NSLOT;              // NN
    int* auxcnt = degc + NN;                         // 1
    uintptr_t pa = (uintptr_t)(auxcnt + 1);
    pa = (pa + 7) & ~(uintptr_t)7;
    int2* aux = (int2*)pa;                           // AUXCAP      (0.5 MB)
    int* colell = (int*)(aux + AUXCAP);              // NN*ELLW     (14.4 MB)
    uintptr_t p = (uintptr_t)(colell + NN * ELLW);
    p = (p + 15) & ~(uintptr_t)15;
    uint2* hb = (uint2*)p;                           // NN*DF bf16  (6.4 MB)
    // bucket array aliases S (dead until first agg overwrites it):
    // 8*6250*64*4B = 12.8MB == sizeof(S) exactly.
    unsigned int* buck = (unsigned int*)S;

    const int fb = NSLICE * NSUB;                    // 160 blocks; slice=bid&7
    const int gb = (NN / 2 * 32 + 255) / 256;        // 6250
    const int ub = (NV4 + 255) / 256;                // 3125

    zero_kernel<<<1, 64, 0, stream>>>(auxcnt, 1);
    ell_part_kernel<<<NBLKA, 256, 0, stream>>>(row, col, buck, auxcnt, aux);
    ell_fill_kernel<<<fb, 1024, 0, stream>>>(buck, degc, colell, auxcnt, aux);
    tobf16_kernel<<<ub, 256, 0, stream>>>(h_in, hb);

    for (int it = 0; it < KIT; ++it) {
        const float* cur = (it == 0) ? h_in : out;
        agg_kernel<<<gb, 256, 0, stream>>>((const uint4*)hb, degc, colell, S,
                                           maxslots + it * NSLOT);
        aux_kernel<<<32, 256, 0, stream>>>(hb, aux, auxcnt, S, maxslots + it * NSLOT);
        update_kernel<<<ub, 256, 0, stream>>>((const float4*)cur, (float4*)out, hb,
                                              (const float4*)S,
                                              maxslots + it * NSLOT);
    }
}

// Round 5
// 377.473 us; speedup vs baseline: 1.2164x; 1.2164x over previous
//
#include <hip/hip_runtime.h>

#define NN 100000
#define NE 1600000
#define DF 32
#define KIT 5
#define MU 0.01f
#define NSLOT 256
#define NV4 (NN * DF / 4)
#define ELLW 36
#define AUXCAP 65536
#define NSLICE 8
#define SLICEN (NN / NSLICE)   // 12500 nodes/slice; colell slice 1.8MB fits XCD L2
#define NSUB 20                // scan-blocks per slice (disjoint segment ranges)
#define NBLKA (NE / 256)       // 6250 blocks in pass A, exactly 256 edges each
#define SEGW 64                // per-block per-slice segment capacity (mean fill 32)
#define INVALID_PK 0xffffffffu // sentinel: rl-field = 32767 >= SLICEN, never valid

typedef float f32x4 __attribute__((ext_vector_type(4)));

// ---------- one-time ELL build (edge_index is iteration-invariant) ----------

__global__ __launch_bounds__(64) void zero_kernel(int* __restrict__ p, int n) {
    int i = blockIdx.x * blockDim.x + threadIdx.x;
    if (i < n) p[i] = 0;
}

// Pass A: single streaming scan; bin edges into 8 slice-buckets. Zero global
// atomics in the common path: wave ballot -> per-wave per-bucket counts -> LDS
// prefix across the 4 waves -> LDS-staged segments -> fully-coalesced 256B
// segment writes. Unused slots carry INVALID_PK sentinels. Segment overflow
// (P ~ 1e-9/block) spills to aux. Edge packed to 4B: (rl<14b)<<17 | c(17b).
// Bucket array (8*NBLKA*SEGW*4B = 12.8MB) aliases S (dead until first agg).
__global__ __launch_bounds__(256) void ell_part_kernel(const int* __restrict__ row,
                                                       const int* __restrict__ col,
                                                       unsigned int* __restrict__ buck,
                                                       int* __restrict__ auxcnt,
                                                       int2* __restrict__ aux) {
    __shared__ int wcnt[4][8];
    __shared__ int woff[4][8];
    __shared__ unsigned int sseg[8][SEGW];       // 2KB staging
    const int t = threadIdx.x;
    const int w = t >> 6;
    const int lane = t & 63;

    ((unsigned int*)sseg)[t] = INVALID_PK;
    ((unsigned int*)sseg)[t + 256] = INVALID_PK;

    const int e = blockIdx.x * 256 + t;          // grid is exactly NE/256
    int b = 8;                                   // out-of-range bucket if guarded off
    unsigned int packed = INVALID_PK;
    int r = 0, c = 0;
    if (e < NE) {
        r = __builtin_nontemporal_load(&row[e]);
        c = __builtin_nontemporal_load(&col[e]);
        b = r / SLICEN;                          // 0..7
        const int rl = r - b * SLICEN;           // < 12500
        packed = ((unsigned int)rl << 17) | (unsigned int)c;
    }

    int myprefix = 0;
    #pragma unroll
    for (int k = 0; k < 8; ++k) {
        const unsigned long long mk = __ballot(b == k);
        if (lane == 0) wcnt[w][k] = __popcll(mk);
        if (k == b) myprefix = __popcll(mk & ((1ull << lane) - 1ull));
    }
    __syncthreads();
    if (t < 32) {
        const int w2 = t >> 3, k = t & 7;
        int o = 0;
        for (int w3 = 0; w3 < w2; ++w3) o += wcnt[w3][k];
        woff[w2][k] = o;
    }
    __syncthreads();

    if (b < 8) {
        const int pos = woff[w][b] + myprefix;
        if (pos < SEGW) {
            sseg[b][pos] = packed;
        } else {
            const int a = atomicAdd(auxcnt, 1);  // a.s. never
            if (a < AUXCAP) aux[a] = make_int2(r, c);
        }
    }
    __syncthreads();

    // write out 8 segments x 256B, fully coalesced (incl. sentinels)
    #pragma unroll
    for (int k = 0; k < 2; ++k) {
        const int idx = t + k * 256;
        const int bb = idx >> 6;
        const int j = idx & 63;
        buck[((size_t)bb * NBLKA + blockIdx.x) * SEGW + j] = sseg[bb][j];
    }
}

// Pass B1 (count): block (s,j) scans a DISJOINT 1/NSUB range of slice s's
// bucket stream (no redundancy — R3's 20x rescan was the regression) and
// histograms ALL 12500 slice nodes in LDS. Dump coalesced as uint16 into
// cnt[s][j][r] (counts <= deg ~45 << 65536 for this input). Zero global RMWs.
__global__ __launch_bounds__(1024) void ell_count_kernel(const unsigned int* __restrict__ buck,
                                                         unsigned short* __restrict__ cnt) {
    __shared__ int hist[SLICEN];                 // 50KB
    const int t = threadIdx.x;
    const int s = blockIdx.x & (NSLICE - 1);
    const int j = blockIdx.x >> 3;               // 0..NSUB-1
    const int lane = t & 63;
    const int wid = t >> 6;                      // 0..15
    const int blo = j * NBLKA / NSUB;
    const int bhi = (j + 1) * NBLKA / NSUB;

    for (int i = t; i < SLICEN; i += 1024) hist[i] = 0;
    __syncthreads();

    const unsigned int* sp = buck + (size_t)s * NBLKA * SEGW;
    int blk = blo + wid;
    unsigned int pk = (blk < bhi) ? sp[(size_t)blk * SEGW + lane] : INVALID_PK;
    for (; blk < bhi; blk += 16) {
        const int nb = blk + 16;
        const unsigned int nx = (nb < bhi) ? sp[(size_t)nb * SEGW + lane] : INVALID_PK;
        const int rl = (int)(pk >> 17);          // sentinel -> 32767, fails check
        if (rl < SLICEN) atomicAdd(&hist[rl], 1);
        pk = nx;
    }
    __syncthreads();
    unsigned short* cp = cnt + ((size_t)s * NSUB + j) * SLICEN;
    for (int i = t; i < SLICEN; i += 1024) cp[i] = (unsigned short)hist[i];
}

// Prefix: per node, exclusive scan of the NSUB per-scan-block counts (in
// place, uint16) + write degc = total. All accesses coalesced (fixed j =>
// consecutive threads hit consecutive addresses).
__global__ __launch_bounds__(256) void ell_prefix_kernel(unsigned short* __restrict__ cnt,
                                                         int* __restrict__ degc) {
    const int i = blockIdx.x * blockDim.x + threadIdx.x;
    if (i >= NN) return;
    const int s = i / SLICEN;
    const int rl = i - s * SLICEN;
    unsigned short* cp = cnt + (size_t)s * NSUB * SLICEN + rl;
    int base = 0;
    #pragma unroll
    for (int j = 0; j < NSUB; ++j) {
        const int v = cp[(size_t)j * SLICEN];
        cp[(size_t)j * SLICEN] = (unsigned short)base;
        base += v;
    }
    degc[i] = base;
}

// Pass B2 (place): preload this block's base offsets into LDS cursors
// (coalesced 25KB read), rescan own range, slot = ldsAtomicAdd(cursor).
// colell writes are scattered only within the XCD-pinned 1.8MB slice ->
// merged in L2, one writeback per line. Spill (pos >= ELLW) -> aux.
// Different j-blocks own disjoint slot ranges per node -> no write races.
__global__ __launch_bounds__(1024) void ell_place_kernel(const unsigned int* __restrict__ buck,
                                                         const unsigned short* __restrict__ cnt,
                                                         int* __restrict__ colell,
                                                         int* __restrict__ auxcnt,
                                                         int2* __restrict__ aux) {
    __shared__ int cur[SLICEN];                  // 50KB cursors
    const int t = threadIdx.x;
    const int s = blockIdx.x & (NSLICE - 1);
    const int j = blockIdx.x >> 3;
    const int lane = t & 63;
    const int wid = t >> 6;
    const int blo = j * NBLKA / NSUB;
    const int bhi = (j + 1) * NBLKA / NSUB;

    const unsigned short* cp = cnt + ((size_t)s * NSUB + j) * SLICEN;
    for (int i = t; i < SLICEN; i += 1024) cur[i] = (int)cp[i];
    __syncthreads();

    const unsigned int* sp = buck + (size_t)s * NBLKA * SEGW;
    int blk = blo + wid;
    unsigned int pk = (blk < bhi) ? sp[(size_t)blk * SEGW + lane] : INVALID_PK;
    for (; blk < bhi; blk += 16) {
        const int nb = blk + 16;
        const unsigned int nx = (nb < bhi) ? sp[(size_t)nb * SEGW + lane] : INVALID_PK;
        const int rl = (int)(pk >> 17);
        if (rl < SLICEN) {
            const int c = (int)(pk & 0x1ffffu);
            const int pos = atomicAdd(&cur[rl], 1);
            const int r = s * SLICEN + rl;
            if (pos < ELLW) {
                colell[r * ELLW + pos] = c;
            } else {
                const int a = atomicAdd(auxcnt, 1);
                if (a < AUXCAP) aux[a] = make_int2(r, c);
            }
        }
        pk = nx;
    }
}

// ---------- bf16 shadow helpers ----------

__device__ __forceinline__ unsigned int pack2bf(float a, float b) {
    unsigned int ua = __float_as_uint(a);
    unsigned int ub = __float_as_uint(b);
    return ((ua + 0x8000u) >> 16) | (((ub + 0x8000u) >> 16) << 16);
}

__device__ __forceinline__ void unpack8(uint4 v, float* f) {
    f[0] = __uint_as_float(v.x << 16);
    f[1] = __uint_as_float(v.x & 0xffff0000u);
    f[2] = __uint_as_float(v.y << 16);
    f[3] = __uint_as_float(v.y & 0xffff0000u);
    f[4] = __uint_as_float(v.z << 16);
    f[5] = __uint_as_float(v.z & 0xffff0000u);
    f[6] = __uint_as_float(v.w << 16);
    f[7] = __uint_as_float(v.w & 0xffff0000u);
}

__global__ __launch_bounds__(256) void tobf16_kernel(const float* __restrict__ h,
                                                     uint2* __restrict__ hb) {
    int i = blockIdx.x * blockDim.x + threadIdx.x;
    if (i < NV4) {
        const f32x4 v = __builtin_nontemporal_load(((const f32x4*)h) + i);
        hb[i] = make_uint2(pack2bf(v.x, v.y), pack2bf(v.z, v.w));
    }
}

// ---------- per-iteration ----------

// One 32-lane group per NODE PAIR. lane = q(3b)*4 + f2(2b); a lane-quad covers
// one 64B bf16 row (uint4/lane). All 10 loads issued before consumption.
// colell reads nt (streamed once); S stores TEMPORAL (update re-reads S soon).
__global__ __launch_bounds__(256) void agg_kernel(const uint4* __restrict__ hb4,
                                                  const int* __restrict__ degc,
                                                  const int* __restrict__ colell,
                                                  float* __restrict__ S,
                                                  int* __restrict__ maxslots) {
    const int lane = threadIdx.x & 31;
    const int q = lane >> 2;
    const int f2 = lane & 3;
    const int pair = (blockIdx.x * blockDim.x + threadIdx.x) >> 5;
    const int n0 = pair * 2;
    const int n1 = n0 + 1;

    const int d0 = min(degc[n0], ELLW);
    const int d1 = min(degc[n1], ELLW);

    // head loads, all independent
    const int ca = (lane < d0) ? __builtin_nontemporal_load(&colell[n0 * ELLW + lane]) : n0;
    const int cb = (lane < d1) ? __builtin_nontemporal_load(&colell[n1 * ELLW + lane]) : n1;
    const uint4 hru0 = hb4[n0 * 4 + f2];
    const uint4 hru1 = hb4[n1 * 4 + f2];

    uint4 u0[4], u1[4];
    #pragma unroll
    for (int j = 0; j < 4; ++j) u0[j] = hb4[__shfl(ca, 8 * j + q, 32) * 4 + f2];
    #pragma unroll
    for (int j = 0; j < 4; ++j) u1[j] = hb4[__shfl(cb, 8 * j + q, 32) * 4 + f2];

    float hr0[8], hr1[8];
    unpack8(hru0, hr0);
    unpack8(hru1, hr1);

    float acc0[8], acc1[8];
    #pragma unroll
    for (int i = 0; i < 8; ++i) { acc0[i] = 0.0f; acc1[i] = 0.0f; }
    float nmax = 0.0f;

    #pragma unroll
    for (int j = 0; j < 4; ++j) {
        float d[8];
        unpack8(u0[j], d);
        float s = 0.0f;
        #pragma unroll
        for (int i = 0; i < 8; ++i) {
            d[i] = hr0[i] - d[i];
            s = fmaf(d[i], d[i], s);
        }
        s += __shfl_xor(s, 1, 32);
        s += __shfl_xor(s, 2, 32);
        const float n = fmaxf(sqrtf(s), 1e-6f);
        nmax = fmaxf(nmax, n);
        const float w = rsqrtf(n);
        #pragma unroll
        for (int i = 0; i < 8; ++i) acc0[i] = fmaf(-d[i], w, acc0[i]);
    }
    #pragma unroll
    for (int j = 0; j < 4; ++j) {
        float d[8];
        unpack8(u1[j], d);
        float s = 0.0f;
        #pragma unroll
        for (int i = 0; i < 8; ++i) {
            d[i] = hr1[i] - d[i];
            s = fmaf(d[i], d[i], s);
        }
        s += __shfl_xor(s, 1, 32);
        s += __shfl_xor(s, 2, 32);
        const float n = fmaxf(sqrtf(s), 1e-6f);
        nmax = fmaxf(nmax, n);
        const float w = rsqrtf(n);
        #pragma unroll
        for (int i = 0; i < 8; ++i) acc1[i] = fmaf(-d[i], w, acc1[i]);
    }

    // tails: edges 32..d-1 (at most one 8-edge step since ELLW=36)
    for (int k = 32; k < d0; k += 8) {
        const int ei = k + q;
        const int c = (ei < d0) ? __builtin_nontemporal_load(&colell[n0 * ELLW + ei]) : n0;
        const uint4 uu = hb4[c * 4 + f2];
        float d[8];
        unpack8(uu, d);
        float s = 0.0f;
        #pragma unroll
        for (int i = 0; i < 8; ++i) {
            d[i] = hr0[i] - d[i];
            s = fmaf(d[i], d[i], s);
        }
        s += __shfl_xor(s, 1, 32);
        s += __shfl_xor(s, 2, 32);
        const float n = fmaxf(sqrtf(s), 1e-6f);
        nmax = fmaxf(nmax, n);
        const float w = rsqrtf(n);
        #pragma unroll
        for (int i = 0; i < 8; ++i) acc0[i] = fmaf(-d[i], w, acc0[i]);
    }
    for (int k = 32; k < d1; k += 8) {
        const int ei = k + q;
        const int c = (ei < d1) ? __builtin_nontemporal_load(&colell[n1 * ELLW + ei]) : n1;
        const uint4 uu = hb4[c * 4 + f2];
        float d[8];
        unpack8(uu, d);
        float s = 0.0f;
        #pragma unroll
        for (int i = 0; i < 8; ++i) {
            d[i] = hr1[i] - d[i];
            s = fmaf(d[i], d[i], s);
        }
        s += __shfl_xor(s, 1, 32);
        s += __shfl_xor(s, 2, 32);
        const float n = fmaxf(sqrtf(s), 1e-6f);
        nmax = fmaxf(nmax, n);
        const float w = rsqrtf(n);
        #pragma unroll
        for (int i = 0; i < 8; ++i) acc1[i] = fmaf(-d[i], w, acc1[i]);
    }

    // cross-quad reduce (quads hold different edges, same feats)
    #pragma unroll
    for (int m = 4; m < 32; m <<= 1) {
        #pragma unroll
        for (int i = 0; i < 8; ++i) {
            acc0[i] += __shfl_xor(acc0[i], m, 32);
            acc1[i] += __shfl_xor(acc1[i], m, 32);
        }
    }
    if (q == 0) {
        ((float4*)S)[n0 * 8 + f2 * 2] = make_float4(acc0[0], acc0[1], acc0[2], acc0[3]);
        ((float4*)S)[n0 * 8 + f2 * 2 + 1] = make_float4(acc0[4], acc0[5], acc0[6], acc0[7]);
        ((float4*)S)[n1 * 8 + f2 * 2] = make_float4(acc1[0], acc1[1], acc1[2], acc1[3]);
        ((float4*)S)[n1 * 8 + f2 * 2 + 1] = make_float4(acc1[4], acc1[5], acc1[6], acc1[7]);
    }

    nmax = fmaxf(nmax, __shfl_xor(nmax, 4, 32));
    nmax = fmaxf(nmax, __shfl_xor(nmax, 8, 32));
    nmax = fmaxf(nmax, __shfl_xor(nmax, 16, 32));
    nmax = fmaxf(nmax, __shfl_xor(nmax, 32, 64));
    if ((threadIdx.x & 63) == 0) {
        // positive floats order like ints; 0xAA poison is negative -> loses
        atomicMax(&maxslots[blockIdx.x & (NSLOT - 1)], __float_as_int(nmax));
    }
}

// overflow edges (deg > ELLW or segment spill): full per-edge norm + atomic
// accumulate into S. Almost surely empty; grid-stride guarantees coverage.
// Runs AFTER agg (its plain S stores) and BEFORE update.
__global__ __launch_bounds__(256) void aux_kernel(const uint2* __restrict__ hb,
                                                  const int2* __restrict__ aux,
                                                  const int* __restrict__ auxcnt,
                                                  float* __restrict__ S,
                                                  int* __restrict__ maxslots) {
    const int n = min(*auxcnt, AUXCAP);
    for (int i = blockIdx.x * blockDim.x + threadIdx.x; i < n;
         i += gridDim.x * blockDim.x) {
        const int r = aux[i].x;
        const int c = aux[i].y;
        float d[32];
        float s = 0.0f;
        for (int j = 0; j < 8; ++j) {
            const uint2 ur = hb[r * 8 + j];
            const uint2 uc = hb[c * 8 + j];
            float fr[4], fc[4];
            fr[0] = __uint_as_float(ur.x << 16);
            fr[1] = __uint_as_float(ur.x & 0xffff0000u);
            fr[2] = __uint_as_float(ur.y << 16);
            fr[3] = __uint_as_float(ur.y & 0xffff0000u);
            fc[0] = __uint_as_float(uc.x << 16);
            fc[1] = __uint_as_float(uc.x & 0xffff0000u);
            fc[2] = __uint_as_float(uc.y << 16);
            fc[3] = __uint_as_float(uc.y & 0xffff0000u);
            #pragma unroll
            for (int k = 0; k < 4; ++k) {
                d[j * 4 + k] = fr[k] - fc[k];
                s = fmaf(d[j * 4 + k], d[j * 4 + k], s);
            }
        }
        const float nn = fmaxf(sqrtf(s), 1e-6f);
        atomicMax(&maxslots[i & (NSLOT - 1)], __float_as_int(nn));
        const float w = rsqrtf(nn);
        for (int f = 0; f < 32; ++f) atomicAdd(&S[r * DF + f], -d[f] * w);
    }
}

// h_out = h_in - MU*sqrt(M)*S (fp32), plus refresh of the bf16 shadow.
__global__ __launch_bounds__(256) void update_kernel(const float4* __restrict__ hcur,
                                                     float4* __restrict__ hnxt,
                                                     uint2* __restrict__ hb,
                                                     const float4* __restrict__ S,
                                                     const int* __restrict__ slots) {
    const int t = threadIdx.x;
    int v = slots[t];
    #pragma unroll
    for (int m = 32; m > 0; m >>= 1) v = max(v, __shfl_xor(v, m, 64));
    __shared__ int sm[4];
    __shared__ float sscale;
    if ((t & 63) == 0) sm[t >> 6] = v;
    __syncthreads();
    if (t == 0) {
        int bm = max(max(sm[0], sm[1]), max(sm[2], sm[3]));
        sscale = MU * sqrtf(__int_as_float(bm));
    }
    __syncthreads();
    const float scale = sscale;
    const int i = blockIdx.x * blockDim.x + t;
    if (i < NV4) {
        const float4 hv = hcur[i];
        const float4 sv = S[i];
        float4 o;
        o.x = hv.x - scale * sv.x;
        o.y = hv.y - scale * sv.y;
        o.z = hv.z - scale * sv.z;
        o.w = hv.w - scale * sv.w;
        hnxt[i] = o;
        hb[i] = make_uint2(pack2bf(o.x, o.y), pack2bf(o.z, o.w));
    }
}

extern "C" void kernel_launch(void* const* d_in, const int* in_sizes, int n_in,
                              void* d_out, int out_size, void* d_ws, size_t ws_size,
                              hipStream_t stream) {
    const float* h_in = (const float*)d_in[0];
    const int* row = (const int*)d_in[1];
    const int* col = row + NE;
    float* out = (float*)d_out;

    float* S = (float*)d_ws;                         // NN*DF f32   (12.8 MB)
    int* maxslots = (int*)(S + NN * DF);             // KIT*NSLOT
    int* degc = maxslots + KIT * NSLOT;              // NN
    int* auxcnt = degc + NN;                         // 1
    uintptr_t pa = (uintptr_t)(auxcnt + 1);
    pa = (pa + 7) & ~(uintptr_t)7;
    int2* aux = (int2*)pa;                           // AUXCAP      (0.5 MB)
    int* colell = (int*)(aux + AUXCAP);              // NN*ELLW     (14.4 MB)
    uintptr_t p = (uintptr_t)(colell + NN * ELLW);
    p = (p + 15) & ~(uintptr_t)15;
    uint2* hb = (uint2*)p;                           // NN*DF bf16  (6.4 MB)
    // bucket array aliases S (dead until first agg): 8*6250*64*4B = 12.8MB.
    unsigned int* buck = (unsigned int*)S;
    // count/prefix table aliases hb (dead until tobf16, which runs after the
    // build): 8*20*12500*2B = 4MB <= 6.4MB.
    unsigned short* cnt = (unsigned short*)hb;

    const int fb = NSLICE * NSUB;                    // 160 blocks; slice=bid&7
    const int pb = (NN + 255) / 256;                 // 391
    const int gb = (NN / 2 * 32 + 255) / 256;        // 6250
    const int ub = (NV4 + 255) / 256;                // 3125

    zero_kernel<<<1, 64, 0, stream>>>(auxcnt, 1);
    ell_part_kernel<<<NBLKA, 256, 0, stream>>>(row, col, buck, auxcnt, aux);
    ell_count_kernel<<<fb, 1024, 0, stream>>>(buck, cnt);
    ell_prefix_kernel<<<pb, 256, 0, stream>>>(cnt, degc);
    ell_place_kernel<<<fb, 1024, 0, stream>>>(buck, cnt, colell, auxcnt, aux);
    tobf16_kernel<<<ub, 256, 0, stream>>>(h_in, hb);

    for (int it = 0; it < KIT; ++it) {
        const float* cur = (it == 0) ? h_in : out;
        agg_kernel<<<gb, 256, 0, stream>>>((const uint4*)hb, degc, colell, S,
                                           maxslots + it * NSLOT);
        aux_kernel<<<32, 256, 0, stream>>>(hb, aux, auxcnt, S, maxslots + it * NSLOT);
        update_kernel<<<ub, 256, 0, stream>>>((const float4*)cur, (float4*)out, hb,
                                              (const float4*)S,
                                              maxslots + it * NSLOT);
    }
}